// Round 9
// baseline (201.070 us; speedup 1.0000x reference)
//
#include <hip/hip_runtime.h>
#include <stdint.h>

// EnergyWell, round 9: R7 (best, 49.3us kernel) + NON-TEMPORAL loads on the
// single-use streams — the last software lever before declaring roofline.
//
// R8 post-mortem: 2x per-wave MLP at 24 waves/CU lost to 1x at 32 waves/CU
// (54 vs 49us): wave-level MLP is not the binder. R4-R8 all pin at
// 2.6-2.9 TB/s effective read. Remaining theory: cache-allocation churn —
// the 128MB avail stream is strictly single-use per replay, but default
// loads allocate L1/L2/L3 lines; eviction churn throttles line fills.
// __builtin_nontemporal_load -> global_load_dwordx4 nt bypasses allocation.
// If this lands ~unchanged, 2.8 TB/s is the HW streaming-read ceiling and
// R7/R9 is the roofline (138MB / 2.8 TB/s ~= 49us).

#define C_WELLS 64

typedef int   vi4 __attribute__((ext_vector_type(4)));
typedef float vf2 __attribute__((ext_vector_type(2)));

template <int CTRL>
__device__ __forceinline__ unsigned long long dpp64(unsigned long long k) {
    int lo = (int)(unsigned)k;
    int hi = (int)(unsigned)(k >> 32);
    lo = __builtin_amdgcn_update_dpp(0, lo, CTRL, 0xF, 0xF, true);
    hi = __builtin_amdgcn_update_dpp(0, hi, CTRL, 0xF, 0xF, true);
    return ((unsigned long long)(unsigned)hi << 32) | (unsigned)lo;
}

__device__ __forceinline__ unsigned long long umin64(unsigned long long a,
                                                     unsigned long long b) {
    return a < b ? a : b;   // v_cmp_lt_u64 + 2 cndmask
}

__global__ __launch_bounds__(256, 8)
void energy_well_kernel(const vf2*  __restrict__ inst_pos,    // N
                        const vf2*  __restrict__ half_sizes,  // N
                        const float* __restrict__ well_boxes, // 64*4 {xl,yl,xh,yh}
                        const vi4*  __restrict__ avail4,      // N*16
                        const float* __restrict__ exponents,  // N
                        float* __restrict__ out,              // N
                        int N, int nT16)
{
    const int lane = threadIdx.x & 63;
    const int sub  = lane & 3;                 // quad member: wells [16sub,16sub+16)
    const int tile = (int)((blockIdx.x * blockDim.x + threadIdx.x) >> 6);
    if (tile >= nT16) return;

    const int i  = tile * 16 + (lane >> 2);    // this quad's instance
    const int ii = i < N ? i : N - 1;          // clamp (tail safety)

    // ---- issue all loads up front (7 VMEM, independent, non-temporal) ----
    const vi4* a = avail4 + ((size_t)ii * 16 + (size_t)sub * 4);
    const vi4 av0 = __builtin_nontemporal_load(a + 0);
    const vi4 av1 = __builtin_nontemporal_load(a + 1);
    const vi4 av2 = __builtin_nontemporal_load(a + 2);
    const vi4 av3 = __builtin_nontemporal_load(a + 3);
    const vf2 p = __builtin_nontemporal_load(inst_pos + ii);
    const vf2 h = __builtin_nontemporal_load(half_sizes + ii);
    const float e = __builtin_nontemporal_load(exponents + ii);

    // x-edges: wave-uniform, compile-time offsets -> s_load (SGPRs, cached)
    float xlv[8], xhv[8];
    #pragma unroll
    for (int ix = 0; ix < 8; ++ix) {
        xlv[ix] = well_boxes[4 * ix + 0];
        xhv[ix] = well_boxes[4 * ix + 2];
    }
    // this lane's two y-rows (iy = 2*sub, 2*sub+1), cached (reused by all waves)
    const float ylA = well_boxes[64 * sub + 1];
    const float yhA = well_boxes[64 * sub + 3];
    const float ylB = well_boxes[64 * sub + 33];
    const float yhB = well_boxes[64 * sub + 35];

    // ---- per-instance separable distances ----
    const float xm = p.x - h.x, xp_ = p.x + h.x;
    const float ym = p.y - h.y, yp_ = p.y + h.y;

    float dxv[8];
    #pragma unroll
    for (int ix = 0; ix < 8; ++ix)
        dxv[ix] = fmaxf(fmaxf(xlv[ix] - xm, xp_ - xhv[ix]), 0.0f);  // v_max3
    const float dyA = fmaxf(fmaxf(ylA - ym, yp_ - yhA), 0.0f);
    const float dyB = fmaxf(fmaxf(ylB - ym, yp_ - yhB), 0.0f);

    // ---- keyed scan: 2 independent chains of 8, then merge ----
    const unsigned gbase = (unsigned)(sub << 4);
    unsigned long long acc0 = ~0ull, acc1 = ~0ull;
    #pragma unroll
    for (int j = 0; j < 4; ++j) {
        const vi4 a4 = (j == 0) ? av0 : (j == 1) ? av1 : (j == 2) ? av2 : av3;
        #pragma unroll
        for (int k = 0; k < 4; ++k) {
            const int c2 = 4 * j + k;                   // local well 0..15
            const int avw = (k == 0) ? a4.x : (k == 1) ? a4.y
                          : (k == 2) ? a4.z : a4.w;
            const float dy   = (c2 < 8) ? dyA : dyB;
            const float dist = dxv[c2 & 7] + dy;
            unsigned long long key =
                (((unsigned long long)__float_as_uint(dist)) << 6)
                | (unsigned long long)(gbase + (unsigned)c2);
            key = avw ? key : ~0ull;                    // mask unavailable
            if (c2 & 1) acc1 = umin64(acc1, key);       // 2 parallel chains
            else        acc0 = umin64(acc0, key);
        }
    }
    unsigned long long kmin = umin64(acc0, acc1);

    // ---- cross-sub (quad) reduce on the VALU pipe via DPP ----
    kmin = umin64(kmin, dpp64<0xB1>(kmin));   // quad_perm [1,0,3,2] : xor 1
    kmin = umin64(kmin, dpp64<0x4E>(kmin));   // quad_perm [2,3,0,1] : xor 2

    // ---- decode winner and store ----
    const int g = (int)(kmin & 63);           // global well index of the min
    const int s = g & 7;                      // ix
    float a0 = (s & 1) ? dxv[1] : dxv[0];
    float a1 = (s & 1) ? dxv[3] : dxv[2];
    float a2 = (s & 1) ? dxv[5] : dxv[4];
    float a3 = (s & 1) ? dxv[7] : dxv[6];
    float b0 = (s & 2) ? a1 : a0;
    float b1 = (s & 2) ? a3 : a2;
    const float dxs = (s & 4) ? b1 : b0;
    const float dys = (g & 8) ? dyB : dyA;    // valid on the winner's sub

    if (((g >> 4) == sub) && (i < N)) {       // unique winner lane per quad
        float energy;
        if (e == 2.0f) energy = dxs * dxs + dys * dys;
        else           energy = powf(dxs, e) + powf(dys, e);
        out[i] = energy;
    }
}

extern "C" void kernel_launch(void* const* d_in, const int* in_sizes, int n_in,
                              void* d_out, int out_size, void* d_ws, size_t ws_size,
                              hipStream_t stream)
{
    // 0: inst_pos (N*2 f32), 1: half_inst_sizes (N*2 f32), 2: inst_areas (UNUSED),
    // 3: well_boxes (64*4 f32), 4: inst_cr_avail_map (N*64 int), 5: exponents (N)
    const vf2*   inst_pos   = (const vf2*)d_in[0];
    const vf2*   half_sizes = (const vf2*)d_in[1];
    const float* well_boxes = (const float*)d_in[3];
    const vi4*   avail4     = (const vi4*)d_in[4];
    const float* exponents  = (const float*)d_in[5];
    float* out = (float*)d_out;

    const int N = in_sizes[5];
    const int nT16 = (N + 15) / 16;            // one 16-instance tile per wave
    const int blocks = (nT16 + 3) / 4;         // 4 waves/block

    energy_well_kernel<<<dim3(blocks), dim3(256), 0, stream>>>(
        inst_pos, half_sizes, well_boxes, avail4, exponents, out, N, nT16);
}

// Round 10
// 195.364 us; speedup vs baseline: 1.0292x; 1.0292x over previous
//
#include <hip/hip_runtime.h>
#include <stdint.h>

// EnergyWell, FINAL (= round 7, the measured best: kernel ~49.3us, bench ~192).
//
// Structure: quad-per-instance (lanes 4i..4i+3 own instance i, 16 wells each),
// separable 8x8 well grid (dx/dy precomputed per edge-row), 64-bit monotone
// key argmin ((bits(dist)<<6)|well — exact, first-index tie-break), DPP
// quad_perm reduce (VALU pipe, no LDS), one 16-instance tile per wave,
// launch_bounds(256,8) -> 32 waves/CU.
//
// Optimization ledger (9 rounds, all falsifiable-predicted):
//  R1 wave-per-instance + shfl argmin        100us  (LDS-pipe chain bound)
//  R2 thread-per-inst + ballot-transpose      82us  (transpose convoy)
//  R3 + separable grid, s_load boxes          66us
//  R5 quad-per-inst, key argmin, DPP          53us
//  R6 perfectly-coalesced variant             61us  (REGRESSED: line-divergence
//                                                    theory falsified)
//  R7 = R5 + 32 waves/CU, lean regs           49us  <- this kernel
//  R8 2 tiles/wave (2x MLP, 24 w/CU)          54us  (MLP not the binder)
//  R9 nontemporal loads                       58us  (L3 serves ~half the
//                                                    stream; bypass hurts)
// Ceiling: 138 MB mandatory read / ~2.8 TB/s blended L3+HBM streaming-read
// rate ~= 49us. VALU audit ~6us; occupancy, MLP, coalescing, NT all probed.

#define C_WELLS 64

template <int CTRL>
__device__ __forceinline__ unsigned long long dpp64(unsigned long long k) {
    int lo = (int)(unsigned)k;
    int hi = (int)(unsigned)(k >> 32);
    lo = __builtin_amdgcn_update_dpp(0, lo, CTRL, 0xF, 0xF, true);
    hi = __builtin_amdgcn_update_dpp(0, hi, CTRL, 0xF, 0xF, true);
    return ((unsigned long long)(unsigned)hi << 32) | (unsigned)lo;
}

__device__ __forceinline__ unsigned long long umin64(unsigned long long a,
                                                     unsigned long long b) {
    return a < b ? a : b;   // v_cmp_lt_u64 + 2 cndmask
}

__global__ __launch_bounds__(256, 8)
void energy_well_kernel(const float2* __restrict__ inst_pos,   // N
                        const float2* __restrict__ half_sizes, // N
                        const float*  __restrict__ well_boxes, // 64*4 {xl,yl,xh,yh}
                        const int4*   __restrict__ avail4,     // N*16
                        const float*  __restrict__ exponents,  // N
                        float* __restrict__ out,               // N
                        int N, int nT16)
{
    const int lane = threadIdx.x & 63;
    const int sub  = lane & 3;                 // quad member: wells [16sub,16sub+16)
    const int tile = (int)((blockIdx.x * blockDim.x + threadIdx.x) >> 6);
    if (tile >= nT16) return;

    const int i  = tile * 16 + (lane >> 2);    // this quad's instance
    const int ii = i < N ? i : N - 1;          // clamp (tail safety)

    // ---- issue all loads up front (7 VMEM, independent) ----
    const int4* a = avail4 + ((size_t)ii * 16 + (size_t)sub * 4);
    const int4 av0 = a[0], av1 = a[1], av2 = a[2], av3 = a[3];
    const float2 p = inst_pos[ii];
    const float2 h = half_sizes[ii];
    const float  e = exponents[ii];

    // x-edges: wave-uniform, compile-time offsets -> s_load (stay in SGPRs)
    float xlv[8], xhv[8];
    #pragma unroll
    for (int ix = 0; ix < 8; ++ix) {
        xlv[ix] = well_boxes[4 * ix + 0];
        xhv[ix] = well_boxes[4 * ix + 2];
    }
    // this lane's two y-rows (iy = 2*sub, 2*sub+1)
    const float ylA = well_boxes[64 * sub + 1];
    const float yhA = well_boxes[64 * sub + 3];
    const float ylB = well_boxes[64 * sub + 33];
    const float yhB = well_boxes[64 * sub + 35];

    // ---- per-instance separable distances ----
    const float xm = p.x - h.x, xp_ = p.x + h.x;
    const float ym = p.y - h.y, yp_ = p.y + h.y;

    float dxv[8];
    #pragma unroll
    for (int ix = 0; ix < 8; ++ix)
        dxv[ix] = fmaxf(fmaxf(xlv[ix] - xm, xp_ - xhv[ix]), 0.0f);  // v_max3
    const float dyA = fmaxf(fmaxf(ylA - ym, yp_ - yhA), 0.0f);
    const float dyB = fmaxf(fmaxf(ylB - ym, yp_ - yhB), 0.0f);

    // ---- keyed scan: 2 independent chains of 8, then merge ----
    const unsigned gbase = (unsigned)(sub << 4);
    unsigned long long acc0 = ~0ull, acc1 = ~0ull;
    #pragma unroll
    for (int j = 0; j < 4; ++j) {
        const int4 a4 = (j == 0) ? av0 : (j == 1) ? av1 : (j == 2) ? av2 : av3;
        #pragma unroll
        for (int k = 0; k < 4; ++k) {
            const int c2 = 4 * j + k;                   // local well 0..15
            const int avw = (k == 0) ? a4.x : (k == 1) ? a4.y
                          : (k == 2) ? a4.z : a4.w;
            const float dy   = (c2 < 8) ? dyA : dyB;
            const float dist = dxv[c2 & 7] + dy;
            unsigned long long key =
                (((unsigned long long)__float_as_uint(dist)) << 6)
                | (unsigned long long)(gbase + (unsigned)c2);
            key = avw ? key : ~0ull;                    // mask unavailable
            if (c2 & 1) acc1 = umin64(acc1, key);       // 2 parallel chains
            else        acc0 = umin64(acc0, key);
        }
    }
    unsigned long long kmin = umin64(acc0, acc1);

    // ---- cross-sub (quad) reduce on the VALU pipe via DPP ----
    kmin = umin64(kmin, dpp64<0xB1>(kmin));   // quad_perm [1,0,3,2] : xor 1
    kmin = umin64(kmin, dpp64<0x4E>(kmin));   // quad_perm [2,3,0,1] : xor 2

    // ---- decode winner and store ----
    const int g = (int)(kmin & 63);           // global well index of the min
    const int s = g & 7;                      // ix
    float a0 = (s & 1) ? dxv[1] : dxv[0];
    float a1 = (s & 1) ? dxv[3] : dxv[2];
    float a2 = (s & 1) ? dxv[5] : dxv[4];
    float a3 = (s & 1) ? dxv[7] : dxv[6];
    float b0 = (s & 2) ? a1 : a0;
    float b1 = (s & 2) ? a3 : a2;
    const float dxs = (s & 4) ? b1 : b0;
    const float dys = (g & 8) ? dyB : dyA;    // valid on the winner's sub

    if (((g >> 4) == sub) && (i < N)) {       // unique winner lane per quad
        float energy;
        if (e == 2.0f) energy = dxs * dxs + dys * dys;
        else           energy = powf(dxs, e) + powf(dys, e);
        out[i] = energy;
    }
}

extern "C" void kernel_launch(void* const* d_in, const int* in_sizes, int n_in,
                              void* d_out, int out_size, void* d_ws, size_t ws_size,
                              hipStream_t stream)
{
    // 0: inst_pos (N*2 f32), 1: half_inst_sizes (N*2 f32), 2: inst_areas (UNUSED),
    // 3: well_boxes (64*4 f32), 4: inst_cr_avail_map (N*64 int), 5: exponents (N)
    const float2* inst_pos   = (const float2*)d_in[0];
    const float2* half_sizes = (const float2*)d_in[1];
    const float*  well_boxes = (const float*)d_in[3];
    const int4*   avail4     = (const int4*)d_in[4];
    const float*  exponents  = (const float*)d_in[5];
    float* out = (float*)d_out;

    const int N = in_sizes[5];
    const int nT16 = (N + 15) / 16;            // one 16-instance tile per wave
    const int blocks = (nT16 + 3) / 4;         // 4 waves/block

    energy_well_kernel<<<dim3(blocks), dim3(256), 0, stream>>>(
        inst_pos, half_sizes, well_boxes, avail4, exponents, out, N, nT16);
}